// Round 3
// baseline (265.376 us; speedup 1.0000x reference)
//
#include <hip/hip_runtime.h>
#include <hip/hip_fp16.h>

namespace {
constexpr int NN   = 10000;   // nodes
constexpr int NE   = 640000;  // edges
constexpr int INC  = 128;     // input channels
constexpr int HIDC = 256;     // hidden channels
constexpr int OUTC = 10;      // output channels
constexpr int NG   = 64;      // graphs
constexpr int DCAP = 128;     // per-node edge-slot cap (deg mean 64, sigma 8 -> 8-sigma bound)
constexpr int SB   = 16;      // scatter blocks (LDS-histogram owners)
constexpr int EPB  = NE / SB; // 40000 edges per scatter block
constexpr int CB   = 240;     // conversion companion blocks
}

typedef __attribute__((ext_vector_type(8))) _Float16 half8;
typedef __attribute__((ext_vector_type(4))) float f32x4;
typedef __attribute__((ext_vector_type(4))) ushort u16x4;

__device__ __forceinline__ ushort f2h(float f) { return __half_as_ushort(__float2half(f)); }
__device__ __forceinline__ float h2f(ushort u) { return __half2float(__ushort_as_half(u)); }

// ---- zero deg cursors + pooled accumulator (workspace is poisoned per call) ----
__global__ __launch_bounds__(256) void zero_kernel(int* __restrict__ deg,
                                                   float* __restrict__ pooled) {
    const int gt = blockIdx.x * 256 + threadIdx.x;
    const int gs = gridDim.x * 256;
    for (int i = gt; i < NN; i += gs) deg[i] = 0;
    for (int i = gt; i < NG * HIDC; i += gs) pooled[i] = 0.0f;
}

// ---- build: blocks [0,SB) = LDS-histogram edge scatter (no per-edge global atomics);
//      blocks [SB,SB+CB) = fp32 -> fp16 conversions of x and W1/W2/W3. ----
__global__ __launch_bounds__(1024) void build_kernel(const int* __restrict__ ei,
                                                     const float* __restrict__ ew,
                                                     int* __restrict__ deg,
                                                     uint* __restrict__ erec,
                                                     const float* __restrict__ x,
                                                     ushort* __restrict__ xh,
                                                     const float* __restrict__ W1,
                                                     ushort* __restrict__ w1h,
                                                     const float* __restrict__ W2,
                                                     ushort* __restrict__ w2h,
                                                     const float* __restrict__ W3,
                                                     ushort* __restrict__ w3h) {
    __shared__ int hist[NN];   // 40 KB: per-dst count, then global base, then cursor
    const int t = threadIdx.x;
    const int bid = blockIdx.x;

    if (bid < SB) {
        // ---- scatter role ----
        const int ebase = bid * EPB;
        for (int i = t; i < NN; i += 1024) hist[i] = 0;
        __syncthreads();

        // pass 1: count dst occurrences (int4-vectorized)
        for (int it = 0; it < 10; ++it) {
            const int vi = it * 4096 + t * 4;
            if (vi < EPB) {
                const int4 d4 = *(const int4*)(ei + NE + ebase + vi);
                atomicAdd(&hist[d4.x], 1);
                atomicAdd(&hist[d4.y], 1);
                atomicAdd(&hist[d4.z], 1);
                atomicAdd(&hist[d4.w], 1);
            }
        }
        __syncthreads();

        // base phase: one global atomic per nonzero bin -> block's base in node row
        for (int b = t; b < NN; b += 1024) {
            const int c = hist[b];
            if (c > 0) hist[b] = atomicAdd(&deg[b], c);
        }
        __syncthreads();

        // pass 2: place records at cursor slots (plain stores)
        for (int it = 0; it < 10; ++it) {
            const int vi = it * 4096 + t * 4;
            if (vi < EPB) {
                const int e = ebase + vi;
                const int4 s4 = *(const int4*)(ei + e);
                const int4 d4 = *(const int4*)(ei + NE + e);
                const float4 w4 = *(const float4*)(ew + e);
                {
                    const int idx = atomicAdd(&hist[d4.x], 1);
                    if (idx < DCAP) erec[((size_t)d4.x << 7) + idx] = ((uint)s4.x << 16) | f2h(w4.x);
                }
                {
                    const int idx = atomicAdd(&hist[d4.y], 1);
                    if (idx < DCAP) erec[((size_t)d4.y << 7) + idx] = ((uint)s4.y << 16) | f2h(w4.y);
                }
                {
                    const int idx = atomicAdd(&hist[d4.z], 1);
                    if (idx < DCAP) erec[((size_t)d4.z << 7) + idx] = ((uint)s4.z << 16) | f2h(w4.z);
                }
                {
                    const int idx = atomicAdd(&hist[d4.w], 1);
                    if (idx < DCAP) erec[((size_t)d4.w << 7) + idx] = ((uint)s4.w << 16) | f2h(w4.w);
                }
            }
        }
        return;
    }

    // ---- conversion role ----
    const int gt = (bid - SB) * 1024 + t;
    const int gs = CB * 1024;
    {
        const int n4 = NN * INC / 4;
        for (int i = gt; i < n4; i += gs) {
            f32x4 v = __builtin_nontemporal_load((const f32x4*)x + i);
            u16x4 o;
#pragma unroll
            for (int j = 0; j < 4; j++) o[j] = f2h(v[j]);
            __builtin_nontemporal_store(o, (u16x4*)xh + i);
        }
    }
    {
        const int n4 = HIDC * INC / 4;
        for (int i = gt; i < n4; i += gs) {
            f32x4 v = __builtin_nontemporal_load((const f32x4*)W1 + i);
            u16x4 o;
#pragma unroll
            for (int j = 0; j < 4; j++) o[j] = f2h(v[j]);
            __builtin_nontemporal_store(o, (u16x4*)w1h + i);
        }
    }
    {
        const int n4 = HIDC * HIDC / 4;
        for (int i = gt; i < n4; i += gs) {
            f32x4 v = __builtin_nontemporal_load((const f32x4*)W2 + i);
            u16x4 o;
#pragma unroll
            for (int j = 0; j < 4; j++) o[j] = f2h(v[j]);
            __builtin_nontemporal_store(o, (u16x4*)w2h + i);
            f32x4 v3 = __builtin_nontemporal_load((const f32x4*)W3 + i);
            u16x4 o3;
#pragma unroll
            for (int j = 0; j < 4; j++) o3[j] = f2h(v3[j]);
            __builtin_nontemporal_store(o3, (u16x4*)w3h + i);
        }
    }
}

// ---- gather F=128: wave = node; 2 edges in flight (32 lanes x ushort4 each) ----
__global__ __launch_bounds__(256) void gather128_kernel(const int* __restrict__ deg,
                                                        const uint* __restrict__ erec,
                                                        const ushort* __restrict__ x,
                                                        ushort* __restrict__ out) {
    constexpr int U = 8;   // edge-pairs per batch (16 edges)
    const int n = blockIdx.x * 4 + (threadIdx.x >> 6);
    if (n >= NN) return;
    const int lane = threadIdx.x & 63;
    const int sub = lane >> 5;
    const int cl  = lane & 31;
    const int d = min(deg[n], DCAP);
    const int beg = n << 7;
    const size_t loff = (size_t)cl * 4;
    const ushort* xr = x + loff;

    float a0, a1, a2, a3;
    {
        u16x4 v = *(const u16x4*)(x + (size_t)n * INC + loff);  // (1+eps)*x self term
        a0 = sub ? 0.f : h2f(v[0]);
        a1 = sub ? 0.f : h2f(v[1]);
        a2 = sub ? 0.f : h2f(v[2]);
        a3 = sub ? 0.f : h2f(v[3]);
    }

    int e = 0;
    for (; e + 2 * U <= d; e += 2 * U) {
        uint rec[U];
#pragma unroll
        for (int u = 0; u < U; u++) rec[u] = erec[beg + e + 2 * u + sub];
        u16x4 v[U];
#pragma unroll
        for (int u = 0; u < U; u++)
            v[u] = *(const u16x4*)(xr + (size_t)(rec[u] >> 16) * INC);
#pragma unroll
        for (int u = 0; u < U; u++) {
            const float w = h2f((ushort)(rec[u] & 0xFFFFu));
            a0 += w * h2f(v[u][0]);
            a1 += w * h2f(v[u][1]);
            a2 += w * h2f(v[u][2]);
            a3 += w * h2f(v[u][3]);
        }
    }
    for (; e + 2 <= d; e += 2) {
        const uint rec = erec[beg + e + sub];
        const float w = h2f((ushort)(rec & 0xFFFFu));
        const u16x4 v = *(const u16x4*)(xr + (size_t)(rec >> 16) * INC);
        a0 += w * h2f(v[0]); a1 += w * h2f(v[1]); a2 += w * h2f(v[2]); a3 += w * h2f(v[3]);
    }
    if (e < d && sub == 0) {
        const uint rec = erec[beg + e];
        const float w = h2f((ushort)(rec & 0xFFFFu));
        const u16x4 v = *(const u16x4*)(xr + (size_t)(rec >> 16) * INC);
        a0 += w * h2f(v[0]); a1 += w * h2f(v[1]); a2 += w * h2f(v[2]); a3 += w * h2f(v[3]);
    }

    a0 += __shfl_xor(a0, 32, 64);
    a1 += __shfl_xor(a1, 32, 64);
    a2 += __shfl_xor(a2, 32, 64);
    a3 += __shfl_xor(a3, 32, 64);
    if (sub == 0) {
        u16x4 o;
        o[0] = f2h(a0); o[1] = f2h(a1); o[2] = f2h(a2); o[3] = f2h(a3);
        __builtin_nontemporal_store(o, (u16x4*)(out + (size_t)n * INC + loff));
    }
}

// ---- F=256 gather, XCD-parity channel-half swizzle + 2 edges/wave-load ----
__global__ __launch_bounds__(256) void gather_half_kernel(const int* __restrict__ deg,
                                                          const uint* __restrict__ erec,
                                                          const ushort* __restrict__ x,
                                                          ushort* __restrict__ out) {
    constexpr int U = 8;
    const int half = blockIdx.x & 1;
    const int n = (blockIdx.x >> 1) * 4 + (threadIdx.x >> 6);
    if (n >= NN) return;
    const int lane = threadIdx.x & 63;
    const int sub = lane >> 5;
    const int cl  = lane & 31;
    const int d = min(deg[n], DCAP);
    const int beg = n << 7;
    const size_t loff = (size_t)half * 128 + cl * 4;
    const ushort* xr = x + loff;

    float a0, a1, a2, a3;
    {
        u16x4 v = *(const u16x4*)(x + (size_t)n * HIDC + loff);  // (1+eps)*x self term
        a0 = sub ? 0.f : h2f(v[0]);
        a1 = sub ? 0.f : h2f(v[1]);
        a2 = sub ? 0.f : h2f(v[2]);
        a3 = sub ? 0.f : h2f(v[3]);
    }

    int e = 0;
    for (; e + 2 * U <= d; e += 2 * U) {
        uint rec[U];
#pragma unroll
        for (int u = 0; u < U; u++) rec[u] = erec[beg + e + 2 * u + sub];
        u16x4 v[U];
#pragma unroll
        for (int u = 0; u < U; u++)
            v[u] = *(const u16x4*)(xr + (size_t)(rec[u] >> 16) * HIDC);
#pragma unroll
        for (int u = 0; u < U; u++) {
            const float w = h2f((ushort)(rec[u] & 0xFFFFu));
            a0 += w * h2f(v[u][0]);
            a1 += w * h2f(v[u][1]);
            a2 += w * h2f(v[u][2]);
            a3 += w * h2f(v[u][3]);
        }
    }
    for (; e + 2 <= d; e += 2) {
        const uint rec = erec[beg + e + sub];
        const float w = h2f((ushort)(rec & 0xFFFFu));
        const u16x4 v = *(const u16x4*)(xr + (size_t)(rec >> 16) * HIDC);
        a0 += w * h2f(v[0]); a1 += w * h2f(v[1]); a2 += w * h2f(v[2]); a3 += w * h2f(v[3]);
    }
    if (e < d && sub == 0) {
        const uint rec = erec[beg + e];
        const float w = h2f((ushort)(rec & 0xFFFFu));
        const u16x4 v = *(const u16x4*)(xr + (size_t)(rec >> 16) * HIDC);
        a0 += w * h2f(v[0]); a1 += w * h2f(v[1]); a2 += w * h2f(v[2]); a3 += w * h2f(v[3]);
    }

    a0 += __shfl_xor(a0, 32, 64);
    a1 += __shfl_xor(a1, 32, 64);
    a2 += __shfl_xor(a2, 32, 64);
    a3 += __shfl_xor(a3, 32, 64);
    if (sub == 0) {
        u16x4 o;
        o[0] = f2h(a0); o[1] = f2h(a1); o[2] = f2h(a2); o[3] = f2h(a3);
        __builtin_nontemporal_store(o, (u16x4*)(out + (size_t)n * HIDC + loff));
    }
}

// ---- MFMA fp16 GEMM: C[M,256] = relu(A[M,K] @ W[256,K]^T + bias), fp16 out ----
template <int K>
__global__ __launch_bounds__(256) void mfma_gemm_kernel(const ushort* __restrict__ A,
                                                        const ushort* __restrict__ Wb,
                                                        const float* __restrict__ bias,
                                                        ushort* __restrict__ C, int M) {
    constexpr int LDW = K + 8;
    __shared__ ushort Ws[64 * LDW];
    const int tid = threadIdx.x;
    const int bm = blockIdx.x * 128;
    const int bn = blockIdx.y * 64;

    constexpr int CPR = K / 8;
    for (int idx = tid; idx < 64 * CPR; idx += 256) {
        int r = idx / CPR, c = idx % CPR;
        uint4 v = *(const uint4*)(Wb + (size_t)(bn + r) * K + c * 8);
        *(uint4*)(&Ws[r * LDW + c * 8]) = v;
    }
    __syncthreads();

    const int wave = tid >> 6;
    const int lane = tid & 63;
    const int lrow = lane & 15;
    const int lq   = lane >> 4;
    const int m0 = bm + wave * 32;

    f32x4 acc[2][4] = {};
    const int r0 = min(m0 + lrow, M - 1);
    const int r1 = min(m0 + 16 + lrow, M - 1);

    for (int k0 = 0; k0 < K; k0 += 32) {
        const int kk = k0 + lq * 8;
        half8 a0 = __builtin_nontemporal_load((const half8*)(A + (size_t)r0 * K + kk));
        half8 a1 = __builtin_nontemporal_load((const half8*)(A + (size_t)r1 * K + kk));
        half8 b[4];
#pragma unroll
        for (int j = 0; j < 4; j++)
            b[j] = *(const half8*)(&Ws[(j * 16 + lrow) * LDW + kk]);
#pragma unroll
        for (int j = 0; j < 4; j++) {
            acc[0][j] = __builtin_amdgcn_mfma_f32_16x16x32_f16(a0, b[j], acc[0][j], 0, 0, 0);
            acc[1][j] = __builtin_amdgcn_mfma_f32_16x16x32_f16(a1, b[j], acc[1][j], 0, 0, 0);
        }
    }

#pragma unroll
    for (int sub = 0; sub < 2; sub++) {
#pragma unroll
        for (int j = 0; j < 4; j++) {
            const int gn = bn + j * 16 + lrow;
            const float bv = bias[gn];
#pragma unroll
            for (int i = 0; i < 4; i++) {
                const int gm = m0 + sub * 16 + lq * 4 + i;
                if (gm < M) {
                    float v = acc[sub][j][i] + bv;
                    v = fmaxf(v, 0.0f);
                    C[(size_t)gm * HIDC + gn] = f2h(v);
                }
            }
        }
    }
}

// ---- layer-3 GEMM with fused mean-pool numerators (no h store) ----
__global__ __launch_bounds__(256) void mfma_gemm_pool_kernel(const ushort* __restrict__ A,
                                                             const ushort* __restrict__ Wb,
                                                             const float* __restrict__ bias,
                                                             const int* __restrict__ batch,
                                                             float* __restrict__ pooled, int M) {
    constexpr int K = HIDC;
    constexpr int LDW = K + 8;
    __shared__ ushort Ws[64 * LDW];
    __shared__ float pl[6][64];
    const int tid = threadIdx.x;
    const int bm = blockIdx.x * 128;
    const int bn = blockIdx.y * 64;

    constexpr int CPR = K / 8;
    for (int idx = tid; idx < 64 * CPR; idx += 256) {
        int r = idx / CPR, c = idx % CPR;
        uint4 v = *(const uint4*)(Wb + (size_t)(bn + r) * K + c * 8);
        *(uint4*)(&Ws[r * LDW + c * 8]) = v;
    }
    for (int i = tid; i < 6 * 64; i += 256) pl[i >> 6][i & 63] = 0.0f;
    __syncthreads();

    const int wave = tid >> 6;
    const int lane = tid & 63;
    const int lrow = lane & 15;
    const int lq   = lane >> 4;
    const int m0 = bm + wave * 32;
    const int g0 = batch[bm];

    f32x4 acc[2][4] = {};
    const int r0 = min(m0 + lrow, M - 1);
    const int r1 = min(m0 + 16 + lrow, M - 1);

    for (int k0 = 0; k0 < K; k0 += 32) {
        const int kk = k0 + lq * 8;
        half8 a0 = __builtin_nontemporal_load((const half8*)(A + (size_t)r0 * K + kk));
        half8 a1 = __builtin_nontemporal_load((const half8*)(A + (size_t)r1 * K + kk));
        half8 b[4];
#pragma unroll
        for (int j = 0; j < 4; j++)
            b[j] = *(const half8*)(&Ws[(j * 16 + lrow) * LDW + kk]);
#pragma unroll
        for (int j = 0; j < 4; j++) {
            acc[0][j] = __builtin_amdgcn_mfma_f32_16x16x32_f16(a0, b[j], acc[0][j], 0, 0, 0);
            acc[1][j] = __builtin_amdgcn_mfma_f32_16x16x32_f16(a1, b[j], acc[1][j], 0, 0, 0);
        }
    }

#pragma unroll
    for (int sub = 0; sub < 2; sub++) {
#pragma unroll
        for (int i = 0; i < 4; i++) {
            const int gm = m0 + sub * 16 + lq * 4 + i;
            if (gm < M) {
                const int gi = min(batch[gm] - g0, 5);
#pragma unroll
                for (int j = 0; j < 4; j++) {
                    const int gn = bn + j * 16 + lrow;
                    float v = acc[sub][j][i] + bias[gn];
                    v = fmaxf(v, 0.0f);
                    atomicAdd(&pl[gi][j * 16 + lrow], v);
                }
            }
        }
    }
    __syncthreads();

    for (int i = tid; i < 6 * 64; i += 256) {
        const int s = i >> 6, col = i & 63;
        const float v = pl[s][col];
        const int gg = g0 + s;
        if (v != 0.0f && gg < NG)
            atomicAdd(&pooled[(size_t)gg * HIDC + bn + col], v);
    }
}

__device__ __forceinline__ int lower_bound_batch(const int* __restrict__ batch, int val) {
    int lo = 0, hi = NN;
    while (lo < hi) {
        int mid = (lo + hi) >> 1;
        if (batch[mid] < val) lo = mid + 1;
        else hi = mid;
    }
    return lo;
}

// ---- head: mean + linear from pooled numerators ----
__global__ __launch_bounds__(256) void head_kernel(const float* __restrict__ pooled,
                                                   const int* __restrict__ batch,
                                                   const float* __restrict__ Wl,
                                                   const float* __restrict__ bl,
                                                   float* __restrict__ out) {
    __shared__ float s[HIDC];
    __shared__ float s2[OUTC][8];
    const int g = blockIdx.x;
    const int t = threadIdx.x;
    const int lo = lower_bound_batch(batch, g);
    const int hi = lower_bound_batch(batch, g + 1);
    const float inv = 1.0f / fmaxf((float)(hi - lo), 1.0f);
    if (t < HIDC) s[t] = pooled[(size_t)g * HIDC + t] * inv;
    __syncthreads();

    if (t < OUTC * 8) {
        const int oc = t >> 3, q = t & 7;
        float acc = 0.f;
        for (int k = q * 32; k < q * 32 + 32; k++)
            acc += s[k] * Wl[(size_t)oc * HIDC + k];
        s2[oc][q] = acc;
    }
    __syncthreads();
    if (t < OUTC) {
        float acc = bl[t];
#pragma unroll
        for (int q = 0; q < 8; q++) acc += s2[t][q];
        out[(size_t)g * OUTC + t] = acc;
    }
}

extern "C" void kernel_launch(void* const* d_in, const int* in_sizes, int n_in,
                              void* d_out, int out_size, void* d_ws, size_t ws_size,
                              hipStream_t stream) {
    const float* x     = (const float*)d_in[0];
    const int*   ei    = (const int*)d_in[1];
    const int*   batch = (const int*)d_in[2];
    const float* ew    = (const float*)d_in[3];
    const float* W1    = (const float*)d_in[4];
    const float* b1    = (const float*)d_in[5];
    const float* W2    = (const float*)d_in[6];
    const float* b2    = (const float*)d_in[7];
    const float* W3    = (const float*)d_in[8];
    const float* b3    = (const float*)d_in[9];
    const float* Wl    = (const float*)d_in[10];
    const float* bl    = (const float*)d_in[11];

    // ---- workspace layout (~21 MB) ----
    char* p = (char*)d_ws;
    ushort* xh     = (ushort*)p; p += (size_t)NN * INC * 2;
    ushort* agg128 = (ushort*)p; p += (size_t)NN * INC * 2;
    ushort* agg256 = (ushort*)p; p += (size_t)NN * HIDC * 2;
    ushort* h      = (ushort*)p; p += (size_t)NN * HIDC * 2;
    ushort* w1h    = (ushort*)p; p += (size_t)HIDC * INC * 2;
    ushort* w2h    = (ushort*)p; p += (size_t)HIDC * HIDC * 2;
    ushort* w3h    = (ushort*)p; p += (size_t)HIDC * HIDC * 2;
    uint*   erec   = (uint*)p;   p += (size_t)NN * DCAP * 4;
    int*    deg    = (int*)p;    p += (size_t)NN * 4;
    float*  pooled = (float*)p;  p += (size_t)NG * HIDC * 4;

    // ---- CSR build: zero cursors, then hierarchical LDS-histogram scatter ----
    zero_kernel<<<32, 256, 0, stream>>>(deg, pooled);
    build_kernel<<<SB + CB, 1024, 0, stream>>>(ei, ew, deg, erec, x, xh,
                                               W1, w1h, W2, w2h, W3, w3h);

    const int gather_grid = (NN + 3) / 4;
    dim3 gemm_grid((NN + 127) / 128, HIDC / 64);

    // ---- layer 1 (K=128) ----
    gather128_kernel<<<gather_grid, 256, 0, stream>>>(deg, erec, xh, agg128);
    mfma_gemm_kernel<INC><<<gemm_grid, 256, 0, stream>>>(agg128, w1h, b1, h, NN);

    // ---- layer 2 (K=256): XCD-parity half swizzle ----
    gather_half_kernel<<<gather_grid * 2, 256, 0, stream>>>(deg, erec, h, agg256);
    mfma_gemm_kernel<HIDC><<<gemm_grid, 256, 0, stream>>>(agg256, w2h, b2, h, NN);

    // ---- layer 3 (K=256): gather then GEMM with fused mean-pool ----
    gather_half_kernel<<<gather_grid * 2, 256, 0, stream>>>(deg, erec, h, agg256);
    mfma_gemm_pool_kernel<<<gemm_grid, 256, 0, stream>>>(agg256, w3h, b3, batch, pooled, NN);

    // ---- head ----
    head_kernel<<<NG, 256, 0, stream>>>(pooled, batch, Wl, bl, (float*)d_out);
}

// Round 4
// 241.092 us; speedup vs baseline: 1.1007x; 1.1007x over previous
//
#include <hip/hip_runtime.h>
#include <hip/hip_fp16.h>

namespace {
constexpr int NN   = 10000;   // nodes
constexpr int NE   = 640000;  // edges
constexpr int INC  = 128;     // input channels
constexpr int HIDC = 256;     // hidden channels
constexpr int OUTC = 10;      // output channels
constexpr int NG   = 64;      // graphs
constexpr int DCAP = 128;     // per-node edge-slot cap (deg mean 64, sigma 8 -> 8-sigma bound)
constexpr int NRG  = 8;       // dst ranges (one per XCD via blockIdx%8 heuristic)
constexpr int RNG  = NN / NRG;    // 1250 nodes per range
constexpr int SLICES = 32;        // edge slices
constexpr int EPSL   = NE / SLICES; // 20000 edges per slice
}

typedef __attribute__((ext_vector_type(8))) _Float16 half8;
typedef __attribute__((ext_vector_type(4))) float f32x4;
typedef __attribute__((ext_vector_type(4))) ushort u16x4;

__device__ __forceinline__ ushort f2h(float f) { return __half_as_ushort(__float2half(f)); }
__device__ __forceinline__ float h2f(ushort u) { return __half2float(__ushort_as_half(u)); }

// ---- zero deg cursors + pooled accumulator (workspace is poisoned per call) ----
__global__ __launch_bounds__(256) void zero_kernel(int* __restrict__ deg,
                                                   float* __restrict__ pooled) {
    const int gt = blockIdx.x * 256 + threadIdx.x;
    const int gs = gridDim.x * 256;
    for (int i = gt; i < NN; i += gs) deg[i] = 0;
    for (int i = gt; i < NG * HIDC; i += gs) pooled[i] = 0.0f;
}

// ---- build: dst-range-partitioned two-scan counting scatter.
// block b: range x = b&7 (-> XCD x under cyclic dispatch; perf heuristic only),
//          slice s = b>>3 (20000 edges). LDS hist = 1250 bins (5 KB).
// Global atomics: one per TOUCHED bin (~1081/block, ~277K total, independent).
// erec/deg slices per range are written only by same-XCD blocks -> no
// cross-XCD partial-line write amplification. Conversion tail grid-strided. ----
__global__ __launch_bounds__(1024) void build_kernel(const int* __restrict__ ei,
                                                     const float* __restrict__ ew,
                                                     int* __restrict__ deg,
                                                     uint* __restrict__ erec,
                                                     const float* __restrict__ x,
                                                     ushort* __restrict__ xh,
                                                     const float* __restrict__ W1,
                                                     ushort* __restrict__ w1h,
                                                     const float* __restrict__ W2,
                                                     ushort* __restrict__ w2h,
                                                     const float* __restrict__ W3,
                                                     ushort* __restrict__ w3h) {
    __shared__ int hist[RNG];
    const int t = threadIdx.x;
    const int rx = blockIdx.x & (NRG - 1);
    const int s  = blockIdx.x >> 3;
    const int nlo = rx * RNG;
    const int ebase = s * EPSL;

    for (int i = t; i < RNG; i += 1024) hist[i] = 0;
    __syncthreads();

    // scan 1: count this range's dsts within this slice (dst stream only)
    for (int vi = t * 4; vi < EPSL; vi += 4096) {
        const int4 d4 = *(const int4*)(ei + NE + ebase + vi);
        int rl;
        rl = d4.x - nlo; if ((uint)rl < (uint)RNG) atomicAdd(&hist[rl], 1);
        rl = d4.y - nlo; if ((uint)rl < (uint)RNG) atomicAdd(&hist[rl], 1);
        rl = d4.z - nlo; if ((uint)rl < (uint)RNG) atomicAdd(&hist[rl], 1);
        rl = d4.w - nlo; if ((uint)rl < (uint)RNG) atomicAdd(&hist[rl], 1);
    }
    __syncthreads();

    // base: one global atomic per touched bin -> fragment base cursor in hist
    for (int b = t; b < RNG; b += 1024) {
        const int c = hist[b];
        if (c > 0) hist[b] = atomicAdd(&deg[nlo + b], c);
    }
    __syncthreads();

    // scan 2: place records at LDS cursor slots (stores are XCD-local)
    for (int vi = t * 4; vi < EPSL; vi += 4096) {
        const int4 s4 = *(const int4*)(ei + ebase + vi);
        const int4 d4 = *(const int4*)(ei + NE + ebase + vi);
        const float4 w4 = *(const float4*)(ew + ebase + vi);
        int rl;
        rl = d4.x - nlo;
        if ((uint)rl < (uint)RNG) {
            const int idx = atomicAdd(&hist[rl], 1);
            if (idx < DCAP) erec[((size_t)(nlo + rl) << 7) + idx] = ((uint)s4.x << 16) | f2h(w4.x);
        }
        rl = d4.y - nlo;
        if ((uint)rl < (uint)RNG) {
            const int idx = atomicAdd(&hist[rl], 1);
            if (idx < DCAP) erec[((size_t)(nlo + rl) << 7) + idx] = ((uint)s4.y << 16) | f2h(w4.y);
        }
        rl = d4.z - nlo;
        if ((uint)rl < (uint)RNG) {
            const int idx = atomicAdd(&hist[rl], 1);
            if (idx < DCAP) erec[((size_t)(nlo + rl) << 7) + idx] = ((uint)s4.z << 16) | f2h(w4.z);
        }
        rl = d4.w - nlo;
        if ((uint)rl < (uint)RNG) {
            const int idx = atomicAdd(&hist[rl], 1);
            if (idx < DCAP) erec[((size_t)(nlo + rl) << 7) + idx] = ((uint)s4.w << 16) | f2h(w4.w);
        }
    }

    // conversion tail: fp32 -> fp16 of x and W1/W2/W3 (grid-stride, all blocks)
    const int gt = blockIdx.x * 1024 + t;
    const int gs = 256 * 1024;
    {
        const int n4 = NN * INC / 4;
        for (int i = gt; i < n4; i += gs) {
            f32x4 v = __builtin_nontemporal_load((const f32x4*)x + i);
            u16x4 o;
#pragma unroll
            for (int j = 0; j < 4; j++) o[j] = f2h(v[j]);
            __builtin_nontemporal_store(o, (u16x4*)xh + i);
        }
    }
    {
        const int n4 = HIDC * INC / 4;
        for (int i = gt; i < n4; i += gs) {
            f32x4 v = __builtin_nontemporal_load((const f32x4*)W1 + i);
            u16x4 o;
#pragma unroll
            for (int j = 0; j < 4; j++) o[j] = f2h(v[j]);
            __builtin_nontemporal_store(o, (u16x4*)w1h + i);
        }
    }
    {
        const int n4 = HIDC * HIDC / 4;
        for (int i = gt; i < n4; i += gs) {
            f32x4 v = __builtin_nontemporal_load((const f32x4*)W2 + i);
            u16x4 o;
#pragma unroll
            for (int j = 0; j < 4; j++) o[j] = f2h(v[j]);
            __builtin_nontemporal_store(o, (u16x4*)w2h + i);
            f32x4 v3 = __builtin_nontemporal_load((const f32x4*)W3 + i);
            u16x4 o3;
#pragma unroll
            for (int j = 0; j < 4; j++) o3[j] = f2h(v3[j]);
            __builtin_nontemporal_store(o3, (u16x4*)w3h + i);
        }
    }
}

// ---- gather F=128: wave = node; 2 edges in flight (32 lanes x ushort4 each) ----
__global__ __launch_bounds__(256) void gather128_kernel(const int* __restrict__ deg,
                                                        const uint* __restrict__ erec,
                                                        const ushort* __restrict__ x,
                                                        ushort* __restrict__ out) {
    constexpr int U = 8;   // edge-pairs per batch (16 edges)
    const int n = blockIdx.x * 4 + (threadIdx.x >> 6);
    if (n >= NN) return;
    const int lane = threadIdx.x & 63;
    const int sub = lane >> 5;
    const int cl  = lane & 31;
    const int d = min(deg[n], DCAP);
    const int beg = n << 7;
    const size_t loff = (size_t)cl * 4;
    const ushort* xr = x + loff;

    float a0, a1, a2, a3;
    {
        u16x4 v = *(const u16x4*)(x + (size_t)n * INC + loff);  // (1+eps)*x self term
        a0 = sub ? 0.f : h2f(v[0]);
        a1 = sub ? 0.f : h2f(v[1]);
        a2 = sub ? 0.f : h2f(v[2]);
        a3 = sub ? 0.f : h2f(v[3]);
    }

    int e = 0;
    for (; e + 2 * U <= d; e += 2 * U) {
        uint rec[U];
#pragma unroll
        for (int u = 0; u < U; u++) rec[u] = erec[beg + e + 2 * u + sub];
        u16x4 v[U];
#pragma unroll
        for (int u = 0; u < U; u++)
            v[u] = *(const u16x4*)(xr + (size_t)(rec[u] >> 16) * INC);
#pragma unroll
        for (int u = 0; u < U; u++) {
            const float w = h2f((ushort)(rec[u] & 0xFFFFu));
            a0 += w * h2f(v[u][0]);
            a1 += w * h2f(v[u][1]);
            a2 += w * h2f(v[u][2]);
            a3 += w * h2f(v[u][3]);
        }
    }
    for (; e + 2 <= d; e += 2) {
        const uint rec = erec[beg + e + sub];
        const float w = h2f((ushort)(rec & 0xFFFFu));
        const u16x4 v = *(const u16x4*)(xr + (size_t)(rec >> 16) * INC);
        a0 += w * h2f(v[0]); a1 += w * h2f(v[1]); a2 += w * h2f(v[2]); a3 += w * h2f(v[3]);
    }
    if (e < d && sub == 0) {
        const uint rec = erec[beg + e];
        const float w = h2f((ushort)(rec & 0xFFFFu));
        const u16x4 v = *(const u16x4*)(xr + (size_t)(rec >> 16) * INC);
        a0 += w * h2f(v[0]); a1 += w * h2f(v[1]); a2 += w * h2f(v[2]); a3 += w * h2f(v[3]);
    }

    a0 += __shfl_xor(a0, 32, 64);
    a1 += __shfl_xor(a1, 32, 64);
    a2 += __shfl_xor(a2, 32, 64);
    a3 += __shfl_xor(a3, 32, 64);
    if (sub == 0) {
        u16x4 o;
        o[0] = f2h(a0); o[1] = f2h(a1); o[2] = f2h(a2); o[3] = f2h(a3);
        __builtin_nontemporal_store(o, (u16x4*)(out + (size_t)n * INC + loff));
    }
}

// ---- F=256 gather, XCD-parity channel-half swizzle + 2 edges/wave-load ----
__global__ __launch_bounds__(256) void gather_half_kernel(const int* __restrict__ deg,
                                                          const uint* __restrict__ erec,
                                                          const ushort* __restrict__ x,
                                                          ushort* __restrict__ out) {
    constexpr int U = 8;
    const int half = blockIdx.x & 1;
    const int n = (blockIdx.x >> 1) * 4 + (threadIdx.x >> 6);
    if (n >= NN) return;
    const int lane = threadIdx.x & 63;
    const int sub = lane >> 5;
    const int cl  = lane & 31;
    const int d = min(deg[n], DCAP);
    const int beg = n << 7;
    const size_t loff = (size_t)half * 128 + cl * 4;
    const ushort* xr = x + loff;

    float a0, a1, a2, a3;
    {
        u16x4 v = *(const u16x4*)(x + (size_t)n * HIDC + loff);  // (1+eps)*x self term
        a0 = sub ? 0.f : h2f(v[0]);
        a1 = sub ? 0.f : h2f(v[1]);
        a2 = sub ? 0.f : h2f(v[2]);
        a3 = sub ? 0.f : h2f(v[3]);
    }

    int e = 0;
    for (; e + 2 * U <= d; e += 2 * U) {
        uint rec[U];
#pragma unroll
        for (int u = 0; u < U; u++) rec[u] = erec[beg + e + 2 * u + sub];
        u16x4 v[U];
#pragma unroll
        for (int u = 0; u < U; u++)
            v[u] = *(const u16x4*)(xr + (size_t)(rec[u] >> 16) * HIDC);
#pragma unroll
        for (int u = 0; u < U; u++) {
            const float w = h2f((ushort)(rec[u] & 0xFFFFu));
            a0 += w * h2f(v[u][0]);
            a1 += w * h2f(v[u][1]);
            a2 += w * h2f(v[u][2]);
            a3 += w * h2f(v[u][3]);
        }
    }
    for (; e + 2 <= d; e += 2) {
        const uint rec = erec[beg + e + sub];
        const float w = h2f((ushort)(rec & 0xFFFFu));
        const u16x4 v = *(const u16x4*)(xr + (size_t)(rec >> 16) * HIDC);
        a0 += w * h2f(v[0]); a1 += w * h2f(v[1]); a2 += w * h2f(v[2]); a3 += w * h2f(v[3]);
    }
    if (e < d && sub == 0) {
        const uint rec = erec[beg + e];
        const float w = h2f((ushort)(rec & 0xFFFFu));
        const u16x4 v = *(const u16x4*)(xr + (size_t)(rec >> 16) * HIDC);
        a0 += w * h2f(v[0]); a1 += w * h2f(v[1]); a2 += w * h2f(v[2]); a3 += w * h2f(v[3]);
    }

    a0 += __shfl_xor(a0, 32, 64);
    a1 += __shfl_xor(a1, 32, 64);
    a2 += __shfl_xor(a2, 32, 64);
    a3 += __shfl_xor(a3, 32, 64);
    if (sub == 0) {
        u16x4 o;
        o[0] = f2h(a0); o[1] = f2h(a1); o[2] = f2h(a2); o[3] = f2h(a3);
        __builtin_nontemporal_store(o, (u16x4*)(out + (size_t)n * HIDC + loff));
    }
}

// ---- MFMA fp16 GEMM: C[M,256] = relu(A[M,K] @ W[256,K]^T + bias), fp16 out ----
template <int K>
__global__ __launch_bounds__(256) void mfma_gemm_kernel(const ushort* __restrict__ A,
                                                        const ushort* __restrict__ Wb,
                                                        const float* __restrict__ bias,
                                                        ushort* __restrict__ C, int M) {
    constexpr int LDW = K + 8;
    __shared__ ushort Ws[64 * LDW];
    const int tid = threadIdx.x;
    const int bm = blockIdx.x * 128;
    const int bn = blockIdx.y * 64;

    constexpr int CPR = K / 8;
    for (int idx = tid; idx < 64 * CPR; idx += 256) {
        int r = idx / CPR, c = idx % CPR;
        uint4 v = *(const uint4*)(Wb + (size_t)(bn + r) * K + c * 8);
        *(uint4*)(&Ws[r * LDW + c * 8]) = v;
    }
    __syncthreads();

    const int wave = tid >> 6;
    const int lane = tid & 63;
    const int lrow = lane & 15;
    const int lq   = lane >> 4;
    const int m0 = bm + wave * 32;

    f32x4 acc[2][4] = {};
    const int r0 = min(m0 + lrow, M - 1);
    const int r1 = min(m0 + 16 + lrow, M - 1);

    for (int k0 = 0; k0 < K; k0 += 32) {
        const int kk = k0 + lq * 8;
        half8 a0 = __builtin_nontemporal_load((const half8*)(A + (size_t)r0 * K + kk));
        half8 a1 = __builtin_nontemporal_load((const half8*)(A + (size_t)r1 * K + kk));
        half8 b[4];
#pragma unroll
        for (int j = 0; j < 4; j++)
            b[j] = *(const half8*)(&Ws[(j * 16 + lrow) * LDW + kk]);
#pragma unroll
        for (int j = 0; j < 4; j++) {
            acc[0][j] = __builtin_amdgcn_mfma_f32_16x16x32_f16(a0, b[j], acc[0][j], 0, 0, 0);
            acc[1][j] = __builtin_amdgcn_mfma_f32_16x16x32_f16(a1, b[j], acc[1][j], 0, 0, 0);
        }
    }

#pragma unroll
    for (int sub = 0; sub < 2; sub++) {
#pragma unroll
        for (int j = 0; j < 4; j++) {
            const int gn = bn + j * 16 + lrow;
            const float bv = bias[gn];
#pragma unroll
            for (int i = 0; i < 4; i++) {
                const int gm = m0 + sub * 16 + lq * 4 + i;
                if (gm < M) {
                    float v = acc[sub][j][i] + bv;
                    v = fmaxf(v, 0.0f);
                    C[(size_t)gm * HIDC + gn] = f2h(v);
                }
            }
        }
    }
}

// ---- layer-3 GEMM with fused mean-pool numerators (no h store) ----
__global__ __launch_bounds__(256) void mfma_gemm_pool_kernel(const ushort* __restrict__ A,
                                                             const ushort* __restrict__ Wb,
                                                             const float* __restrict__ bias,
                                                             const int* __restrict__ batch,
                                                             float* __restrict__ pooled, int M) {
    constexpr int K = HIDC;
    constexpr int LDW = K + 8;
    __shared__ ushort Ws[64 * LDW];
    __shared__ float pl[6][64];
    const int tid = threadIdx.x;
    const int bm = blockIdx.x * 128;
    const int bn = blockIdx.y * 64;

    constexpr int CPR = K / 8;
    for (int idx = tid; idx < 64 * CPR; idx += 256) {
        int r = idx / CPR, c = idx % CPR;
        uint4 v = *(const uint4*)(Wb + (size_t)(bn + r) * K + c * 8);
        *(uint4*)(&Ws[r * LDW + c * 8]) = v;
    }
    for (int i = tid; i < 6 * 64; i += 256) pl[i >> 6][i & 63] = 0.0f;
    __syncthreads();

    const int wave = tid >> 6;
    const int lane = tid & 63;
    const int lrow = lane & 15;
    const int lq   = lane >> 4;
    const int m0 = bm + wave * 32;
    const int g0 = batch[bm];

    f32x4 acc[2][4] = {};
    const int r0 = min(m0 + lrow, M - 1);
    const int r1 = min(m0 + 16 + lrow, M - 1);

    for (int k0 = 0; k0 < K; k0 += 32) {
        const int kk = k0 + lq * 8;
        half8 a0 = __builtin_nontemporal_load((const half8*)(A + (size_t)r0 * K + kk));
        half8 a1 = __builtin_nontemporal_load((const half8*)(A + (size_t)r1 * K + kk));
        half8 b[4];
#pragma unroll
        for (int j = 0; j < 4; j++)
            b[j] = *(const half8*)(&Ws[(j * 16 + lrow) * LDW + kk]);
#pragma unroll
        for (int j = 0; j < 4; j++) {
            acc[0][j] = __builtin_amdgcn_mfma_f32_16x16x32_f16(a0, b[j], acc[0][j], 0, 0, 0);
            acc[1][j] = __builtin_amdgcn_mfma_f32_16x16x32_f16(a1, b[j], acc[1][j], 0, 0, 0);
        }
    }

#pragma unroll
    for (int sub = 0; sub < 2; sub++) {
#pragma unroll
        for (int i = 0; i < 4; i++) {
            const int gm = m0 + sub * 16 + lq * 4 + i;
            if (gm < M) {
                const int gi = min(batch[gm] - g0, 5);
#pragma unroll
                for (int j = 0; j < 4; j++) {
                    const int gn = bn + j * 16 + lrow;
                    float v = acc[sub][j][i] + bias[gn];
                    v = fmaxf(v, 0.0f);
                    atomicAdd(&pl[gi][j * 16 + lrow], v);
                }
            }
        }
    }
    __syncthreads();

    for (int i = tid; i < 6 * 64; i += 256) {
        const int s = i >> 6, col = i & 63;
        const float v = pl[s][col];
        const int gg = g0 + s;
        if (v != 0.0f && gg < NG)
            atomicAdd(&pooled[(size_t)gg * HIDC + bn + col], v);
    }
}

__device__ __forceinline__ int lower_bound_batch(const int* __restrict__ batch, int val) {
    int lo = 0, hi = NN;
    while (lo < hi) {
        int mid = (lo + hi) >> 1;
        if (batch[mid] < val) lo = mid + 1;
        else hi = mid;
    }
    return lo;
}

// ---- head: mean + linear from pooled numerators ----
__global__ __launch_bounds__(256) void head_kernel(const float* __restrict__ pooled,
                                                   const int* __restrict__ batch,
                                                   const float* __restrict__ Wl,
                                                   const float* __restrict__ bl,
                                                   float* __restrict__ out) {
    __shared__ float s[HIDC];
    __shared__ float s2[OUTC][8];
    const int g = blockIdx.x;
    const int t = threadIdx.x;
    const int lo = lower_bound_batch(batch, g);
    const int hi = lower_bound_batch(batch, g + 1);
    const float inv = 1.0f / fmaxf((float)(hi - lo), 1.0f);
    if (t < HIDC) s[t] = pooled[(size_t)g * HIDC + t] * inv;
    __syncthreads();

    if (t < OUTC * 8) {
        const int oc = t >> 3, q = t & 7;
        float acc = 0.f;
        for (int k = q * 32; k < q * 32 + 32; k++)
            acc += s[k] * Wl[(size_t)oc * HIDC + k];
        s2[oc][q] = acc;
    }
    __syncthreads();
    if (t < OUTC) {
        float acc = bl[t];
#pragma unroll
        for (int q = 0; q < 8; q++) acc += s2[t][q];
        out[(size_t)g * OUTC + t] = acc;
    }
}

extern "C" void kernel_launch(void* const* d_in, const int* in_sizes, int n_in,
                              void* d_out, int out_size, void* d_ws, size_t ws_size,
                              hipStream_t stream) {
    const float* x     = (const float*)d_in[0];
    const int*   ei    = (const int*)d_in[1];
    const int*   batch = (const int*)d_in[2];
    const float* ew    = (const float*)d_in[3];
    const float* W1    = (const float*)d_in[4];
    const float* b1    = (const float*)d_in[5];
    const float* W2    = (const float*)d_in[6];
    const float* b2    = (const float*)d_in[7];
    const float* W3    = (const float*)d_in[8];
    const float* b3    = (const float*)d_in[9];
    const float* Wl    = (const float*)d_in[10];
    const float* bl    = (const float*)d_in[11];

    // ---- workspace layout (~21 MB) ----
    char* p = (char*)d_ws;
    ushort* xh     = (ushort*)p; p += (size_t)NN * INC * 2;
    ushort* agg128 = (ushort*)p; p += (size_t)NN * INC * 2;
    ushort* agg256 = (ushort*)p; p += (size_t)NN * HIDC * 2;
    ushort* h      = (ushort*)p; p += (size_t)NN * HIDC * 2;
    ushort* w1h    = (ushort*)p; p += (size_t)HIDC * INC * 2;
    ushort* w2h    = (ushort*)p; p += (size_t)HIDC * HIDC * 2;
    ushort* w3h    = (ushort*)p; p += (size_t)HIDC * HIDC * 2;
    uint*   erec   = (uint*)p;   p += (size_t)NN * DCAP * 4;
    int*    deg    = (int*)p;    p += (size_t)NN * 4;
    float*  pooled = (float*)p;  p += (size_t)NG * HIDC * 4;

    // ---- CSR build: zero cursors, then range-partitioned two-scan scatter ----
    zero_kernel<<<32, 256, 0, stream>>>(deg, pooled);
    build_kernel<<<NRG * SLICES, 1024, 0, stream>>>(ei, ew, deg, erec, x, xh,
                                                    W1, w1h, W2, w2h, W3, w3h);

    const int gather_grid = (NN + 3) / 4;
    dim3 gemm_grid((NN + 127) / 128, HIDC / 64);

    // ---- layer 1 (K=128) ----
    gather128_kernel<<<gather_grid, 256, 0, stream>>>(deg, erec, xh, agg128);
    mfma_gemm_kernel<INC><<<gemm_grid, 256, 0, stream>>>(agg128, w1h, b1, h, NN);

    // ---- layer 2 (K=256): XCD-parity half swizzle ----
    gather_half_kernel<<<gather_grid * 2, 256, 0, stream>>>(deg, erec, h, agg256);
    mfma_gemm_kernel<HIDC><<<gemm_grid, 256, 0, stream>>>(agg256, w2h, b2, h, NN);

    // ---- layer 3 (K=256): gather then GEMM with fused mean-pool ----
    gather_half_kernel<<<gather_grid * 2, 256, 0, stream>>>(deg, erec, h, agg256);
    mfma_gemm_pool_kernel<<<gemm_grid, 256, 0, stream>>>(agg256, w3h, b3, batch, pooled, NN);

    // ---- head ----
    head_kernel<<<NG, 256, 0, stream>>>(pooled, batch, Wl, bl, (float*)d_out);
}